// Round 12
// baseline (18.993 us; speedup 1.0000x reference)
//
#include <hip/hip_runtime.h>

// Dihedral2Coord — 2 molecules per wave, BOTH as full-width W=64 scans,
// software-interleaved for 2-way ILP. The scan's serial bottleneck is
// ds_bpermute (shuffle) latency + VALU dep chains; two independent scan
// DAGs in one lane program let the scheduler fill each other's stall slots
// while keeping 8 waves/CU of TLP for the cold HBM phase (unlike deeper
// lane-packing, which trades waves away).
//
// final[m] = P_{m-3}(pos0[m]); P_k = B_0∘...∘B_k (LOCAL-frame step
// rotations; dihedrals are rigid-invariant so phi_k comes from pos0 alone).

#define NK 128
#define NM 512
#define NMOL 4096
#define TPB 256
#define WPB 4        // waves per block
#define MPW 2        // molecules per wave (interleaved, each W=64)
// grid = NMOL/(WPB*MPW) = 512

struct Aff { float qw, qx, qy, qz, tx, ty, tz; };

__device__ __forceinline__ void qrot(float qw, float qx, float qy, float qz,
                                     float vx, float vy, float vz,
                                     float& ox, float& oy, float& oz) {
    const float ux = qy*vz - qz*vy + qw*vx;
    const float uy = qz*vx - qx*vz + qw*vy;
    const float uz = qx*vy - qy*vx + qw*vz;
    ox = vx + 2.f*(qy*uz - qz*uy);
    oy = vy + 2.f*(qz*ux - qx*uz);
    oz = vz + 2.f*(qx*uy - qy*ux);
}

// (Q∘P)(x) = Q(P(x))
__device__ __forceinline__ Aff aff_compose(const Aff& Q, const Aff& P) {
    Aff r;
    r.qw = Q.qw*P.qw - Q.qx*P.qx - Q.qy*P.qy - Q.qz*P.qz;
    r.qx = Q.qw*P.qx + Q.qx*P.qw + Q.qy*P.qz - Q.qz*P.qy;
    r.qy = Q.qw*P.qy - Q.qx*P.qz + Q.qy*P.qw + Q.qz*P.qx;
    r.qz = Q.qw*P.qz + Q.qx*P.qy - Q.qy*P.qx + Q.qz*P.qw;
    float rx, ry, rz;
    qrot(Q.qw, Q.qx, Q.qy, Q.qz, P.tx, P.ty, P.tz, rx, ry, rz);
    r.tx = rx + Q.tx; r.ty = ry + Q.ty; r.tz = rz + Q.tz;
    return r;
}

// Step rotation about axis J->K by (theta + dihedral(I,J,K,L)), pivot J.
// Validated formula (R10/R11, absmax 0.125).
__device__ __forceinline__ Aff build_step(const float* a, float th) {
    const float ijx=a[3]-a[0], ijy=a[4]-a[1],  ijz=a[5]-a[2];
    const float jkx=a[6]-a[3], jky=a[7]-a[4],  jkz=a[8]-a[5];
    const float klx=a[9]-a[6], kly=a[10]-a[7], klz=a[11]-a[8];
    const float n1x=ijy*jkz-ijz*jky, n1y=ijz*jkx-ijx*jkz, n1z=ijx*jky-ijy*jkx;
    const float n2x=jky*klz-jkz*kly, n2y=jkz*klx-jkx*klz, n2z=jkx*kly-jky*klx;
    const float L1=n1x*n1x+n1y*n1y+n1z*n1z;
    const float L2=n2x*n2x+n2y*n2y+n2z*n2z;
    const float dnn=n1x*n2x+n1y*n2y+n1z*n2z;
    const float cxx=n2y*n1z-n2z*n1y, cxy=n2z*n1x-n2x*n1z, cxz=n2x*n1y-n2y*n1x;
    const float g  = cxx*jkx + cxy*jky + cxz*jkz;
    const float Ljk = jkx*jkx+jky*jky+jkz*jkz;
    const float ira = rsqrtf(fmaxf(Ljk, 1e-24f));
    const float r12 = rsqrtf(fmaxf(L1*L2, 1e-30f));
    const float cphi = dnn*r12;
    const float sphi = g*r12*ira;
    const float sth = __sinf(th), cth = __cosf(th);
    const float c = cth*cphi - sth*sphi;
    const float s = sth*cphi + cth*sphi;
    const float hc = sqrtf(fmaxf(0.f, 0.5f*(1.f + c)));
    const float hs = copysignf(sqrtf(fmaxf(0.f, 0.5f*(1.f - c))), s);
    const float hsa = hs*ira;
    Aff b;
    b.qw = hc; b.qx = jkx*hsa; b.qy = jky*hsa; b.qz = jkz*hsa;
    float rx, ry, rz;
    qrot(b.qw, b.qx, b.qy, b.qz, a[3], a[4], a[5], rx, ry, rz);
    b.tx = a[3]-rx; b.ty = a[4]-ry; b.tz = a[5]-rz;
    return b;
}

#define SHFL_AFF_UP(D, S, off)                                           \
    D.qw = __shfl_up(S.qw, off, 64); D.qx = __shfl_up(S.qx, off, 64);    \
    D.qy = __shfl_up(S.qy, off, 64); D.qz = __shfl_up(S.qz, off, 64);    \
    D.tx = __shfl_up(S.tx, off, 64); D.ty = __shfl_up(S.ty, off, 64);    \
    D.tz = __shfl_up(S.tz, off, 64);

__global__ __launch_bounds__(TPB, 2) void dihedral_ilp2_kernel(
    const float* __restrict__ theta,  // (NMOL, NK)
    const float* __restrict__ pos0,   // (NMOL, NM, 3)
    float* __restrict__ out)          // (NMOL, NM, 3)
{
    const int tid  = threadIdx.x;
    const int lane = tid & 63;
    const int wid  = tid >> 6;
    const int molA = (blockIdx.x * WPB + wid) * MPW;
    const int molB = molA + 1;

    const float4* __restrict__ pbA = (const float4*)(pos0 + (size_t)molA * (NM*3));
    float4*       __restrict__ obA = (float4*)(out  + (size_t)molA * (NM*3));
    const float4* __restrict__ pbB = (const float4*)(pos0 + (size_t)molB * (NM*3));
    float4*       __restrict__ obB = (float4*)(out  + (size_t)molB * (NM*3));

    __shared__ float sA[WPB][MPW][400];   // pos0 atoms 0..131
    __shared__ float sO[WPB][MPW][400];   // final atoms 0..131

    const bool ex   = (lane < 35);
    const bool has2 = (lane < 31);   // tail tasks 64..94

    // ---- t0: head A+B, theta A+B, tails A ----
    float4 hA0 = pbA[lane];
    float4 hA1; if (ex) hA1 = pbA[64 + lane];
    float4 hB0 = pbB[lane];
    float4 hB1; if (ex) hB1 = pbB[64 + lane];
    const float2 thA = ((const float2*)(theta + (size_t)molA * NK))[lane];
    const float2 thB = ((const float2*)(theta + (size_t)molB * NK))[lane];
    float4 TA0, TA1, TA2, TA3, TA4, TA5;
    { const int b = 99 + 3*lane; TA0 = pbA[b]; TA1 = pbA[b+1]; TA2 = pbA[b+2]; }
    if (has2) { const int b = 99 + 3*(64 + lane); TA3 = pbA[b]; TA4 = pbA[b+1]; TA5 = pbA[b+2]; }

    // stage heads (same-wave DS ordering, no barrier)
    float4* sA4A = (float4*)sA[wid][0];
    float4* sA4B = (float4*)sA[wid][1];
    sA4A[lane] = hA0; if (ex) sA4A[64 + lane] = hA1;
    sA4B[lane] = hB0; if (ex) sA4B[64 + lane] = hB1;

    // lane k: atoms 2k..2k+4 (15 floats) for each molecule
    float AA[16], AB[16];
    {
        const float2* a2 = (const float2*)&sA[wid][0][lane * 6];
        const float2* b2 = (const float2*)&sA[wid][1][lane * 6];
        #pragma unroll
        for (int i = 0; i < 7; ++i) {
            const float2 va = a2[i]; AA[2*i] = va.x; AA[2*i+1] = va.y;
            const float2 vb = b2[i]; AB[2*i] = vb.x; AB[2*i+1] = vb.y;
        }
        AA[14] = sA[wid][0][lane * 6 + 14];
        AB[14] = sA[wid][1][lane * 6 + 14];
    }

    // ---- build steps (independent A/B chains, compiler interleaves) ----
    Aff BevA = build_step(&AA[0], thA.x);
    Aff BevB = build_step(&AB[0], thB.x);
    Aff BodA = build_step(&AA[3], thA.y);
    Aff BodB = build_step(&AB[3], thB.y);
    Aff SA_ = aff_compose(BevA, BodA);
    Aff SB_ = aff_compose(BevB, BodB);

    // ---- fused dual scan: each round's two composes are independent ----
    #pragma unroll
    for (int off = 1; off < 64; off <<= 1) {
        Aff QA; SHFL_AFF_UP(QA, SA_, off);
        Aff QB; SHFL_AFF_UP(QB, SB_, off);
        if (lane >= off) SA_ = aff_compose(QA, SA_);
        if (lane >= off) SB_ = aff_compose(QB, SB_);
    }
    Aff EA; SHFL_AFF_UP(EA, SA_, 1);
    Aff EB; SHFL_AFF_UP(EB, SB_, 1);
    if (lane == 0) {
        EA.qw = 1.f; EA.qx = EA.qy = EA.qz = 0.f; EA.tx = EA.ty = EA.tz = 0.f;
        EB.qw = 1.f; EB.qx = EB.qy = EB.qz = 0.f; EB.tx = EB.ty = EB.tz = 0.f;
    }
    Aff PeA = aff_compose(EA, BevA);   // P_{2k}
    Aff PeB = aff_compose(EB, BevB);

    // ---- issue tails B now (latency hides under emit/stores of A) ----
    float4 TB0, TB1, TB2, TB3, TB4, TB5;
    { const int b = 99 + 3*lane; TB0 = pbB[b]; TB1 = pbB[b+1]; TB2 = pbB[b+2]; }
    if (has2) { const int b = 99 + 3*(64 + lane); TB3 = pbB[b]; TB4 = pbB[b+1]; TB5 = pbB[b+2]; }

    // ---- emit head atoms into sO ----
    {
        float ox, oy, oz;
        float* opA = &sO[wid][0][lane * 6 + 9];
        qrot(PeA.qw, PeA.qx, PeA.qy, PeA.qz, AA[9], AA[10], AA[11], ox, oy, oz);
        opA[0] = ox + PeA.tx; opA[1] = oy + PeA.ty; opA[2] = oz + PeA.tz;
        qrot(SA_.qw, SA_.qx, SA_.qy, SA_.qz, AA[12], AA[13], AA[14], ox, oy, oz);
        opA[3] = ox + SA_.tx; opA[4] = oy + SA_.ty; opA[5] = oz + SA_.tz;
        float* opB = &sO[wid][1][lane * 6 + 9];
        qrot(PeB.qw, PeB.qx, PeB.qy, PeB.qz, AB[9], AB[10], AB[11], ox, oy, oz);
        opB[0] = ox + PeB.tx; opB[1] = oy + PeB.ty; opB[2] = oz + PeB.tz;
        qrot(SB_.qw, SB_.qx, SB_.qy, SB_.qz, AB[12], AB[13], AB[14], ox, oy, oz);
        opB[3] = ox + SB_.tx; opB[4] = oy + SB_.ty; opB[5] = oz + SB_.tz;
    }
    if (lane < 9) { sO[wid][0][lane] = sA[wid][0][lane]; sO[wid][1][lane] = sA[wid][1][lane]; }
    if (lane == 63) {
        float ox, oy, oz;
        qrot(SA_.qw, SA_.qx, SA_.qy, SA_.qz, sA[wid][0][393], sA[wid][0][394], sA[wid][0][395], ox, oy, oz);
        sO[wid][0][393] = ox + SA_.tx; sO[wid][0][394] = oy + SA_.ty; sO[wid][0][395] = oz + SA_.tz;
        qrot(SB_.qw, SB_.qx, SB_.qy, SB_.qz, sA[wid][1][393], sA[wid][1][394], sA[wid][1][395], ox, oy, oz);
        sO[wid][1][393] = ox + SB_.tx; sO[wid][1][394] = oy + SB_.ty; sO[wid][1][395] = oz + SB_.tz;
    }

    // ---- F = P_127 broadcast (register-only) for both molecules ----
    Aff FA, FB;
    FA.qw = __shfl(SA_.qw, 63, 64); FA.qx = __shfl(SA_.qx, 63, 64);
    FA.qy = __shfl(SA_.qy, 63, 64); FA.qz = __shfl(SA_.qz, 63, 64);
    FA.tx = __shfl(SA_.tx, 63, 64); FA.ty = __shfl(SA_.ty, 63, 64);
    FA.tz = __shfl(SA_.tz, 63, 64);
    FB.qw = __shfl(SB_.qw, 63, 64); FB.qx = __shfl(SB_.qx, 63, 64);
    FB.qy = __shfl(SB_.qy, 63, 64); FB.qz = __shfl(SB_.qz, 63, 64);
    FB.tx = __shfl(SB_.tx, 63, 64); FB.ty = __shfl(SB_.ty, 63, 64);
    FB.tz = __shfl(SB_.tz, 63, 64);

    #define MAT_OF(F, f00,f01,f02,f10,f11,f12,f20,f21,f22)                   \
        const float f00 = 1.f - 2.f*(F.qy*F.qy + F.qz*F.qz);                 \
        const float f01 = 2.f*(F.qx*F.qy - F.qw*F.qz);                       \
        const float f02 = 2.f*(F.qx*F.qz + F.qw*F.qy);                       \
        const float f10 = 2.f*(F.qx*F.qy + F.qw*F.qz);                       \
        const float f11 = 1.f - 2.f*(F.qx*F.qx + F.qz*F.qz);                 \
        const float f12 = 2.f*(F.qy*F.qz - F.qw*F.qx);                       \
        const float f20 = 2.f*(F.qx*F.qz - F.qw*F.qy);                       \
        const float f21 = 2.f*(F.qy*F.qz + F.qw*F.qx);                       \
        const float f22 = 1.f - 2.f*(F.qx*F.qx + F.qy*F.qy);
    MAT_OF(FA, a00,a01,a02,a10,a11,a12,a20,a21,a22)
    MAT_OF(FB, b00,b01,b02,b10,b11,b12,b20,b21,b22)
    #undef MAT_OF

    #define TAIL_EMIT(ob4, b, va, vb, vc, f00,f01,f02,f10,f11,f12,f20,f21,f22, FT) \
    do {                                                                      \
        const float x0=va.x, y0=va.y, z0=va.z;                                \
        const float x1=va.w, y1=vb.x, z1=vb.y;                                \
        const float x2=vb.z, y2=vb.w, z2=vc.x;                                \
        const float x3=vc.y, y3=vc.z, z3=vc.w;                                \
        float4 o0, o1, o2;                                                    \
        o0.x = f00*x0+f01*y0+f02*z0+FT.tx; o0.y = f10*x0+f11*y0+f12*z0+FT.ty; \
        o0.z = f20*x0+f21*y0+f22*z0+FT.tz; o0.w = f00*x1+f01*y1+f02*z1+FT.tx; \
        o1.x = f10*x1+f11*y1+f12*z1+FT.ty; o1.y = f20*x1+f21*y1+f22*z1+FT.tz; \
        o1.z = f00*x2+f01*y2+f02*z2+FT.tx; o1.w = f10*x2+f11*y2+f12*z2+FT.ty; \
        o2.x = f20*x2+f21*y2+f22*z2+FT.tz; o2.y = f00*x3+f01*y3+f02*z3+FT.tx; \
        o2.z = f10*x3+f11*y3+f12*z3+FT.ty; o2.w = f20*x3+f21*y3+f22*z3+FT.tz; \
        ob4[(b)] = o0; ob4[(b)+1] = o1; ob4[(b)+2] = o2;                      \
    } while (0)

    // ---- tails A (regs ready) ----
    TAIL_EMIT(obA, 99 + 3*lane, TA0, TA1, TA2, a00,a01,a02,a10,a11,a12,a20,a21,a22, FA);
    if (has2) TAIL_EMIT(obA, 99 + 3*(64 + lane), TA3, TA4, TA5, a00,a01,a02,a10,a11,a12,a20,a21,a22, FA);

    // ---- store heads from LDS ----
    const float4* sO4A = (const float4*)sO[wid][0];
    const float4* sO4B = (const float4*)sO[wid][1];
    obA[lane] = sO4A[lane]; if (ex) obA[64 + lane] = sO4A[64 + lane];
    obB[lane] = sO4B[lane]; if (ex) obB[64 + lane] = sO4B[64 + lane];

    // ---- tails B (loads issued pre-emit; latency already covered) ----
    TAIL_EMIT(obB, 99 + 3*lane, TB0, TB1, TB2, b00,b01,b02,b10,b11,b12,b20,b21,b22, FB);
    if (has2) TAIL_EMIT(obB, 99 + 3*(64 + lane), TB3, TB4, TB5, b00,b01,b02,b10,b11,b12,b20,b21,b22, FB);
    #undef TAIL_EMIT
}

extern "C" void kernel_launch(void* const* d_in, const int* in_sizes, int n_in,
                              void* d_out, int out_size, void* d_ws, size_t ws_size,
                              hipStream_t stream) {
    const float* theta = (const float*)d_in[0];  // input (N,K) fp32
    const float* pos0  = (const float*)d_in[1];  // pos0 (N,M,3) fp32
    float* out = (float*)d_out;                  // (N,M,3) fp32
    dihedral_ilp2_kernel<<<NMOL / (WPB * MPW), TPB, 0, stream>>>(theta, pos0, out);
}